// Round 23
// baseline (47.891 us; speedup 1.0000x reference)
//
#include <hip/hip_runtime.h>

// Conv2d 5x5, C=3, O=1, stride 1, pad 2, N=256, H=W=224, +bias.
// R23 = R22 with the phase-count bug fixed: a 2-band chain is 6 phases
// (2 bands x 3 channels), NOT 12. R22's P/3 walked 4 bands -> OOB row
// writes into the next image (absmax 3.09). Ideas themselves unchanged:
//   1) persistent 2-band chains: grid 1792 (8*224, 7 chains/CU) -> half the
//      exposed stage prologues vs R21's 3584 blocks.
//   2) x-pads live in LDS: dwords {2,3,228,229} of every row zeroed ONCE
//      (staging writes only 4..227) -> no lo/hi cndmasks; raw 11-dword
//      windows. g=0 reads dwords 2,3 = zeros; g=31 reads 228,229 = zeros.
//   3) s_setprio(1) around the FMA cluster: 4 waves/SIMD from 4 different
//      blocks at desynced phases -> compute waves pre-empt stage waves.
// Kept: BAND=16, RST=232 (232%32=8), +4-dword shift, channel-phase dbuf
// pipeline (literal phases), 7-wide x 2-tall full-lane mapping, stage via
// gl_lds16 (wave-uniform dest, lane<56), XCD swizzle, no launch_bounds
// min-arg.
// Bounds check: P in [0,5] -> band_ in {b0, b0+1}, b0 = (bid%7)*2 <= 12 ->
// bands 0..13, each exactly once. Window max dword = 7*31+2+10 = 229.

namespace {

constexpr int Hc = 224, Wc = 224, Cc = 3;
constexpr int HW = Hc * Wc;
constexpr int CHW = Cc * HW;
constexpr int BAND = 16;              // output rows per band
constexpr int SROWS = BAND + 4;       // 20 staged rows per (band, channel)
constexpr int RST = 232;              // LDS row stride (dwords); 232%32 = 8
constexpr int BUFD = SROWS * RST;     // 4640 dwords = 18560 B per buffer
constexpr int CPI = 7;                // chains per image (2 bands each)
constexpr int BLK = 256;

__device__ __forceinline__ void gl_lds16(const float* g, float* l) {
  __builtin_amdgcn_global_load_lds(
      (const __attribute__((address_space(1))) void*)g,
      (__attribute__((address_space(3))) void*)l, 16, 0, 0);
}

__global__ __launch_bounds__(BLK) void conv5x5_r23(
    const float* __restrict__ x, const float* __restrict__ wl,
    const float* __restrict__ bptr, float* __restrict__ out) {
  __shared__ __align__(16) float sm[2 * BUFD];   // 37120 B

  const int tid = threadIdx.x;
  const int lane = tid & 63;
  const int wv = tid >> 6;

  // Bijective XCD swizzle: 1792 = 8 * 224.
  const int cpx = gridDim.x >> 3;
  const int bid = (blockIdx.x & 7) * cpx + (blockIdx.x >> 3);
  const int n = bid / CPI;                 // image
  const int b0 = (bid % CPI) * 2;          // first band of this 2-band chain

  // Weights: wave-uniform, compile-time offsets -> SGPRs.
  float w[Cc][5][5];
#pragma unroll
  for (int c = 0; c < Cc; ++c)
#pragma unroll
    for (int i = 0; i < 25; ++i) w[c][i / 5][i % 5] = wl[c * 25 + i];
  const float bias = bptr[0];

  const float* xn = x + (size_t)n * CHW;
  float* outn = out + (size_t)n * HW;

  // Compute roles: 256 threads = 32 col-groups (7 outputs wide) x 8
  // row-groups (2 rows). Window base = LDS dword 7g+2 (global 7g-2).
  const int g = tid & 31;
  const int tg = tid >> 5;
  const int rdo = g * 7 + 2;

  float acc[2][7];                         // 2 rows x 7 cols, static indexed

  // ---- one-time x-pad zeroing: dwords {2,3,228,229} of all 40 rows ----
  // (staging writes only dwords 4..227; window max dword = 229)
  if (tid < 160) {
    const int buf = tid / 80;
    const int rem = tid % 80;
    const int row = rem >> 2;
    const int j = rem & 3;
    const int dw = (j < 2) ? (2 + j) : (226 + j);   // 2,3,228,229
    sm[buf * BUFD + row * RST + dw] = 0.f;
  }

  // Stage phase P (literal 0..5): 20 rows of channel P%3, band b0+P/3,
  // into buffer P&1. Wave wv owns rows {wv+4i}. LDS dest = wave-uniform row
  // base +4 dwords; HW adds lane*16 (lanes >= 56 masked). OOB rows (y pad)
  // zero-filled (vector store, lanes < 56 -> dwords 4..227, pads untouched).
#define STAGE_P(P)                                                            \
  do {                                                                        \
    const int band_ = b0 + (P) / 3;                                           \
    const float* gch_ = xn + (size_t)((P) % 3) * HW;                          \
    float* smb_ = sm + ((P) & 1) * BUFD;                                      \
    _Pragma("unroll") for (int i_ = 0; i_ < 5; ++i_) {                        \
      const int r_ = wv + 4 * i_;                                             \
      const int gy_ = band_ * BAND - 2 + r_;                                  \
      float* ld_ = smb_ + r_ * RST + 4;                                       \
      if (gy_ >= 0 && gy_ < Hc) {                                             \
        if (lane < 56)                                                        \
          gl_lds16(gch_ + (size_t)gy_ * Wc + lane * 4, ld_);                  \
      } else {                                                                \
        if (lane < 56)                                                        \
          *(float4*)(ld_ + lane * 4) = make_float4(0.f, 0.f, 0.f, 0.f);       \
      }                                                                       \
    }                                                                         \
  } while (0)

  // Compute phase P (literal 0..5) from buffer P&1. Thread reads LDS rows
  // tg*2 + jj, jj=0..5; output row r (0..1) taps jj = r..r+4 (ky = jj-r).
  // Window = raw 11-dword read (x-pads are real zeros in LDS).
#define COMPUTE_P(P)                                                          \
  do {                                                                        \
    constexpr int ch_ = (P) % 3;                                              \
    const int band_ = b0 + (P) / 3;                                           \
    const float* smb_ = sm + ((P) & 1) * BUFD;                                \
    if (ch_ == 0) {                                                           \
      _Pragma("unroll") for (int r_ = 0; r_ < 2; ++r_)                        \
          _Pragma("unroll") for (int c_ = 0; c_ < 7; ++c_)                    \
              acc[r_][c_] = 0.f;                                              \
    }                                                                         \
    __builtin_amdgcn_s_setprio(1);                                            \
    _Pragma("unroll") for (int jj_ = 0; jj_ < 6; ++jj_) {                     \
      const float* rp_ = smb_ + (tg * 2 + jj_) * RST + rdo;                   \
      float win_[11];                                                         \
      _Pragma("unroll") for (int j_ = 0; j_ < 11; ++j_) win_[j_] = rp_[j_];   \
      _Pragma("unroll") for (int r_ = 0; r_ < 2; ++r_) {                      \
        if (r_ <= jj_ && jj_ - r_ <= 4) {                                     \
          _Pragma("unroll") for (int kx_ = 0; kx_ < 5; ++kx_) {               \
            const float wv_ = w[ch_][jj_ - r_][kx_];                          \
            _Pragma("unroll") for (int c_ = 0; c_ < 7; ++c_) {                \
              acc[r_][c_] = fmaf(win_[c_ + kx_], wv_, acc[r_][c_]);           \
            }                                                                 \
          }                                                                   \
        }                                                                     \
      }                                                                       \
    }                                                                         \
    __builtin_amdgcn_s_setprio(0);                                            \
    if (ch_ == 2) {                                                           \
      _Pragma("unroll") for (int r_ = 0; r_ < 2; ++r_) {                      \
        const int gy_ = band_ * BAND + tg * 2 + r_;                           \
        float* op_ = outn + (size_t)gy_ * Wc + g * 7;                         \
        _Pragma("unroll") for (int c_ = 0; c_ < 7; ++c_)                      \
            op_[c_] = acc[r_][c_] + bias;                                     \
      }                                                                       \
    }                                                                         \
  } while (0)

  // ---- persistent 2-band pipeline: 6 literal phases, 1 prologue ----
  STAGE_P(0);
  __syncthreads(); STAGE_P(1); COMPUTE_P(0);
  __syncthreads(); STAGE_P(2); COMPUTE_P(1);
  __syncthreads(); STAGE_P(3); COMPUTE_P(2);
  __syncthreads(); STAGE_P(4); COMPUTE_P(3);
  __syncthreads(); STAGE_P(5); COMPUTE_P(4);
  __syncthreads();             COMPUTE_P(5);

#undef STAGE_P
#undef COMPUTE_P
}

}  // namespace

extern "C" void kernel_launch(void* const* d_in, const int* in_sizes, int n_in,
                              void* d_out, int out_size, void* d_ws, size_t ws_size,
                              hipStream_t stream) {
  const float* x  = (const float*)d_in[0];   // [N,3,224,224] f32
  const float* wl = (const float*)d_in[1];   // [1,75] f32
  const float* b  = (const float*)d_in[2];   // [1] f32
  float* out = (float*)d_out;                // [N,224,224] f32

  const int N = out_size / HW;               // 256
  const int nblk = N * CPI;                  // 1792 = 8 * 224

  conv5x5_r23<<<nblk, BLK, 0, stream>>>(x, wl, b, out);
}

// Round 24
// 42.317 us; speedup vs baseline: 1.1317x; 1.1317x over previous
//
#include <hip/hip_runtime.h>

// Conv2d 5x5, C=3, O=1, stride 1, pad 2, N=256, H=W=224, +bias.
// R24 = R21 (42.5us best) + LDS-resident x-pads ONLY.
//   R23 post-mortem: the 3-way bundle (persistent chains + pads + setprio)
//   regressed to 47.9. Unbundling: chains doubled per-CU work granularity
//   (7 long blocks over 4 residency slots -> coarse tail), setprio is
//   0-to-negative on barrier-locked structures. The pad trick is the only
//   component with no plausible harm mechanism -> test it alone.
// Change vs R21: zero dwords {2,3,228,229} of all 40 LDS rows once at kernel
// start (staging writes only dwords 4..227, so pads persist); delete lo/hi
// cndmasks; windows are raw 11-dword reads. -24 selects/phase/thread.
// Kept from R21: grid 3584 (8*448 XCD swizzle), 1 band/block, 3 literal
// phases, BAND=16, RST=232 (232%32=8), +4-dword shift, 7-wide x 2-tall
// full-lane mapping, stage via gl_lds16 (wave-uniform dest, lane<56),
// 4 blocks/CU, no launch_bounds min-arg, no setprio.

namespace {

constexpr int Hc = 224, Wc = 224, Cc = 3;
constexpr int HW = Hc * Wc;
constexpr int CHW = Cc * HW;
constexpr int BAND = 16;              // output rows per band (= per block)
constexpr int SROWS = BAND + 4;       // 20 staged rows per (band, channel)
constexpr int RST = 232;              // LDS row stride (dwords); 232%32 = 8
constexpr int BUFD = SROWS * RST;     // 4640 dwords = 18560 B per buffer
constexpr int SPI = Hc / BAND;        // 14 bands (strips) per image
constexpr int BLK = 256;

__device__ __forceinline__ void gl_lds16(const float* g, float* l) {
  __builtin_amdgcn_global_load_lds(
      (const __attribute__((address_space(1))) void*)g,
      (__attribute__((address_space(3))) void*)l, 16, 0, 0);
}

__global__ __launch_bounds__(BLK) void conv5x5_r24(
    const float* __restrict__ x, const float* __restrict__ wl,
    const float* __restrict__ bptr, float* __restrict__ out) {
  __shared__ __align__(16) float sm[2 * BUFD];   // 37120 B

  const int tid = threadIdx.x;
  const int lane = tid & 63;
  const int wv = tid >> 6;

  // Bijective XCD swizzle: 3584 = 8 * 448.
  const int cpx = gridDim.x >> 3;
  const int bid = (blockIdx.x & 7) * cpx + (blockIdx.x >> 3);
  const int n = bid / SPI;                 // image
  const int band = bid % SPI;              // band index (16 rows)

  // Weights: wave-uniform, compile-time offsets -> SGPRs.
  float w[Cc][5][5];
#pragma unroll
  for (int c = 0; c < Cc; ++c)
#pragma unroll
    for (int i = 0; i < 25; ++i) w[c][i / 5][i % 5] = wl[c * 25 + i];
  const float bias = bptr[0];

  const float* xn = x + (size_t)n * CHW;
  float* outn = out + (size_t)n * HW;

  // Compute roles: 256 threads = 32 col-groups (7 outputs wide) x 8
  // row-groups (2 rows). Window base = LDS dword 7g+2 (global dword j lives
  // at LDS j+4; window = global 7g-2..7g+8 = LDS 7g+2..7g+12).
  const int g = tid & 31;
  const int tg = tid >> 5;
  const int rdo = g * 7 + 2;

  float acc[2][7];                         // 2 rows x 7 cols, static indexed

  // ---- one-time x-pad zeroing: dwords {2,3,228,229} of all 40 rows ----
  // (staging writes only dwords 4..227; window max dword = 7*31+2+10 = 229;
  //  g=0 reads dwords 2,3 = zeros, g=31 reads 228,229 = zeros)
  if (tid < 160) {
    const int buf = tid / 80;
    const int rem = tid % 80;
    const int row = rem >> 2;
    const int j = rem & 3;
    const int dw = (j < 2) ? (2 + j) : (226 + j);   // 2,3,228,229
    sm[buf * BUFD + row * RST + dw] = 0.f;
  }

  // Stage phase P (literal): 20 rows of channel P, band `band`, into buffer
  // P&1. Wave wv owns rows {wv, wv+4, wv+8, wv+12, wv+16}. LDS dest is the
  // wave-uniform row base (+4-dword shift); HW adds lane*16 (lanes >= 56
  // masked; row data = dwords 4..227). OOB rows (y pad: band 0 r<2, band 13
  // r>=18) zero-filled via vector store (lanes < 56 -> pads untouched).
#define STAGE_P(P)                                                            \
  do {                                                                        \
    const float* gch_ = xn + (size_t)(P) * HW;                                \
    float* smb_ = sm + ((P) & 1) * BUFD;                                      \
    _Pragma("unroll") for (int i_ = 0; i_ < 5; ++i_) {                        \
      const int r_ = wv + 4 * i_;                                             \
      const int gy_ = band * BAND - 2 + r_;                                   \
      float* ld_ = smb_ + r_ * RST + 4;                                       \
      if (gy_ >= 0 && gy_ < Hc) {                                             \
        if (lane < 56)                                                        \
          gl_lds16(gch_ + (size_t)gy_ * Wc + lane * 4, ld_);                  \
      } else {                                                                \
        if (lane < 56)                                                        \
          *(float4*)(ld_ + lane * 4) = make_float4(0.f, 0.f, 0.f, 0.f);       \
      }                                                                       \
    }                                                                         \
  } while (0)

  // Compute phase P (literal) from buffer P&1. Thread reads LDS rows
  // tg*2 + jj, jj=0..5; output row r (0..1) taps jj = r..r+4 (ky = jj-r).
  // Window = raw 11-dword read (x-pads are real zeros in LDS; no masks).
#define COMPUTE_P(P)                                                          \
  do {                                                                        \
    constexpr int ch_ = (P);                                                  \
    const float* smb_ = sm + ((P) & 1) * BUFD;                                \
    if (ch_ == 0) {                                                           \
      _Pragma("unroll") for (int r_ = 0; r_ < 2; ++r_)                        \
          _Pragma("unroll") for (int c_ = 0; c_ < 7; ++c_)                    \
              acc[r_][c_] = 0.f;                                              \
    }                                                                         \
    _Pragma("unroll") for (int jj_ = 0; jj_ < 6; ++jj_) {                     \
      const float* rp_ = smb_ + (tg * 2 + jj_) * RST + rdo;                   \
      float win_[11];                                                         \
      _Pragma("unroll") for (int j_ = 0; j_ < 11; ++j_) win_[j_] = rp_[j_];   \
      _Pragma("unroll") for (int r_ = 0; r_ < 2; ++r_) {                      \
        if (r_ <= jj_ && jj_ - r_ <= 4) {                                     \
          _Pragma("unroll") for (int kx_ = 0; kx_ < 5; ++kx_) {               \
            const float wv_ = w[ch_][jj_ - r_][kx_];                          \
            _Pragma("unroll") for (int c_ = 0; c_ < 7; ++c_) {                \
              acc[r_][c_] = fmaf(win_[c_ + kx_], wv_, acc[r_][c_]);           \
            }                                                                 \
          }                                                                   \
        }                                                                     \
      }                                                                       \
    }                                                                         \
    if (ch_ == 2) {                                                           \
      _Pragma("unroll") for (int r_ = 0; r_ < 2; ++r_) {                      \
        const int gy_ = band * BAND + tg * 2 + r_;                            \
        float* op_ = outn + (size_t)gy_ * Wc + g * 7;                         \
        _Pragma("unroll") for (int c_ = 0; c_ < 7; ++c_)                      \
            op_[c_] = acc[r_][c_] + bias;                                     \
      }                                                                       \
    }                                                                         \
  } while (0)

  // ---- pipeline: stage(P+1) flies under compute(P); 3 barriers total ----
  STAGE_P(0);
  __syncthreads(); STAGE_P(1); COMPUTE_P(0);
  __syncthreads(); STAGE_P(2); COMPUTE_P(1);
  __syncthreads();             COMPUTE_P(2);

#undef STAGE_P
#undef COMPUTE_P
}

}  // namespace

extern "C" void kernel_launch(void* const* d_in, const int* in_sizes, int n_in,
                              void* d_out, int out_size, void* d_ws, size_t ws_size,
                              hipStream_t stream) {
  const float* x  = (const float*)d_in[0];   // [N,3,224,224] f32
  const float* wl = (const float*)d_in[1];   // [1,75] f32
  const float* b  = (const float*)d_in[2];   // [1] f32
  float* out = (float*)d_out;                // [N,224,224] f32

  const int N = out_size / HW;               // 256
  const int nblk = N * SPI;                  // 3584 = 8 * 448

  conv5x5_r24<<<nblk, BLK, 0, stream>>>(x, wl, b, out);
}